// Round 2
// baseline (4548.156 us; speedup 1.0000x reference)
//
#include <hip/hip_runtime.h>
#include <cstddef>

// Problem constants
constexpr int BATCH = 128;
constexpr int T     = 16;             // coarse grid
constexpr int ROWS  = BATCH * T * T;  // 32768
constexpr int WID   = 100;            // network width
constexpr int NB    = 50;             // residual blocks
constexpr int WJ    = 128;            // padded j extent (col dim of weight tiles)
constexpr int RPW   = 64;             // rows per workgroup in chain kernel

// ---------------------------------------------------------------------------
// Prep: pad weights [50][100][100] -> [50][100][128] (zero pad cols), with a
// k-parity swizzle on j (j ^= 4 for odd k) so the chain kernel's ds_read_b128
// of 8-col groups lands on disjoint 4-bank windows across the two k-rows a
// wave reads simultaneously. Also per-block column sums of Wa (b1 fold).
// ---------------------------------------------------------------------------
__global__ __launch_bounds__(256) void prep_kernel(
    const float* __restrict__ Wa, const float* __restrict__ Wb,
    float* __restrict__ wpadA, float* __restrict__ wpadB,
    float* __restrict__ csA) {
  const int bid = blockIdx.x;          // 0..99
  const int bk  = bid % NB;
  const bool isA = bid < NB;
  const float* src = (isA ? Wa : Wb) + (size_t)bk * (WID * WID);
  float* dst = (isA ? wpadA : wpadB) + (size_t)bk * (WID * WJ);
  for (int i = threadIdx.x; i < WID * WJ; i += 256) {
    int k = i >> 7;          // / 128
    int j = i & (WJ - 1);
    // store element (k, j) at swizzled position j ^ (4*(k&1))
    dst[(i & ~(WJ - 1)) | (j ^ ((k & 1) << 2))] = (j < WID) ? src[k * WID + j] : 0.0f;
  }
  if (isA) {
    for (int j = threadIdx.x; j < WJ; j += 256) {
      float s = 0.0f;
      if (j < WID) {
        for (int k = 0; k < WID; ++k) s += src[k * WID + j];
      }
      csA[bk * WJ + j] = s;   // unswizzled
    }
  }
}

// ---------------------------------------------------------------------------
// First layer: gather 45-wide stencil rows, x0 = relu(flat @ W0)
// ---------------------------------------------------------------------------
__global__ __launch_bounds__(256) void first_layer_kernel(
    const float* __restrict__ inp, const float* __restrict__ W0,
    float* __restrict__ x0) {
  __shared__ float w0s[45 * WID];
  for (int i = threadIdx.x; i < 45 * WID; i += 256) w0s[i] = W0[i];
  __syncthreads();

  const int rq  = threadIdx.x >> 2;   // 0..63
  const int cq  = threadIdx.x & 3;    // 0..3
  const int row = blockIdx.x * 64 + rq;
  const int b   = row >> 8;
  const int t1  = (row >> 4) & 15;
  const int t2  = row & 15;
  const int g1  = 2 * t1, g2 = 2 * t2;
  const int g1m = (g1 + 31) & 31, g2m = (g2 + 31) & 31;
  const float* base = inp + (size_t)b * (32 * 32 * 9);
  const float* p0 = base + ((g1 + 1) * 32 + g2) * 9;
  const float* p1 = base + (g1m * 32 + g2) * 9;
  const float* p2 = base + (g1 * 32 + (g2 + 1)) * 9;
  const float* p3 = base + (g1 * 32 + g2m) * 9;
  const float* p4 = base + (g1 * 32 + g2) * 9;

  float f[45];
#pragma unroll
  for (int q = 0; q < 9; ++q) {
    f[q]      = p0[q];
    f[9 + q]  = p1[q];
    f[18 + q] = p2[q];
    f[27 + q] = p3[q];
    f[36 + q] = p4[q];
  }

  float acc[25];
#pragma unroll
  for (int j = 0; j < 25; ++j) acc[j] = 0.0f;
  const int j0 = cq * 25;
#pragma unroll
  for (int k = 0; k < 45; ++k) {
    const float fv = f[k];
#pragma unroll
    for (int j = 0; j < 25; ++j) acc[j] += fv * w0s[k * WID + j0 + j];
  }
  float* orow = x0 + (size_t)row * WID + j0;
#pragma unroll
  for (int j = 0; j < 25; ++j) orow[j] = fmaxf(acc[j], 0.0f);
}

// ---------------------------------------------------------------------------
// Chain: 50 residual blocks fused. 512 WGs x 256 threads, 64 rows/WG.
// Tile 8x8 per thread, in-wave k-split (lane bit 5: even/odd k), shfl reduce.
// LDS: xsT[100][64], vsT[100][64]  (k-major, XOR-swizzled r), wbuf[50][128].
// Stage = issue-early / write-late register staging (latency hidden).
// ---------------------------------------------------------------------------
__global__ __launch_bounds__(256, 2) void chain_kernel(
    float* __restrict__ x0,
    const float* __restrict__ wpadA, const float* __restrict__ wpadB,
    const float* __restrict__ csA,
    const float* __restrict__ B1, const float* __restrict__ B2,
    const float* __restrict__ B3, const float* __restrict__ B4,
    const float* __restrict__ M) {
  __shared__ __align__(16) float xsT[WID * 64];   // 25600 B
  __shared__ __align__(16) float vsT[WID * 64];   // 25600 B
  __shared__ __align__(16) float wbuf[50 * WJ];   // 25600 B

  const int tid   = threadIdx.x;
  const int lane  = tid & 63;
  const int wid   = tid >> 6;       // wave id 0..3
  const int ksb   = lane >> 5;      // k-split half: 0 = even k, 1 = odd k
  const int halfl = lane & 31;
  const int rg    = halfl >> 4;     // 0..1
  const int colg  = halfl & 15;     // 0..15
  const int r0    = wid * 16 + rg * 8;   // 8-row group base (0..56)
  const int j0    = colg * 8;            // 8-col group base (0..120)
  const int rbase = blockIdx.x * RPW;

  // ---- register staging (7 float4 per thread covers 50x128 floats) ----
  float4 wreg[7];
  const bool has7 = (tid < 64);
  auto issue_stage = [&](const float* src) {
    const float4* s4 = (const float4*)src;
#pragma unroll
    for (int it = 0; it < 6; ++it) wreg[it] = s4[tid + 256 * it];
    if (has7) wreg[6] = s4[tid + 1536];
  };
  auto write_stage = [&]() {
    float4* w4 = (float4*)wbuf;
#pragma unroll
    for (int it = 0; it < 6; ++it) w4[tid + 256 * it] = wreg[it];
    if (has7) w4[tid + 1536] = wreg[6];
  };

  // prologue: fire first weight-chunk loads, then transpose-fill xsT
  issue_stage(wpadA);
  for (int i = tid; i < RPW * WID; i += 256) {
    const int k = i >> 6, r = i & 63;
    const int sw = ((k >> 3) & 1) << 2;
    xsT[k * 64 + (r ^ sw)] = x0[(size_t)(rbase + r) * WID + k];
  }

  float acc[8][8];
  auto zero_acc = [&]() {
#pragma unroll
    for (int rr = 0; rr < 8; ++rr)
#pragma unroll
      for (int jj = 0; jj < 8; ++jj) acc[rr][jj] = 0.0f;
  };

  // bases: lane handles k = kbase + 2*kk + ksb
  const float* w0p = &wbuf[ksb * WJ + j0 + 4 * ksb];        // cols j0..j0+3
  const float* w1p = &wbuf[ksb * WJ + j0 + 4 - 4 * ksb];    // cols j0+4..j0+7

  auto kloop = [&](const float* xT, const int kbase) {
    const float* bx = &xT[ksb * 64 + r0];
#pragma unroll
    for (int kk = 0; kk < 25; ++kk) {
      const int keven = kbase + 2 * kk;                // compile-time
      const int sw = (keven >> 3) & 1;                 // compile-time
      const float4 va = *(const float4*)&bx[keven * 64];
      const float4 vb = *(const float4*)&bx[keven * 64 + 4];
      const float4 xlo4 = sw ? vb : va;                // rows r0..r0+3
      const float4 xhi4 = sw ? va : vb;                // rows r0+4..r0+7
      const float4 wa = *(const float4*)&w0p[kk * 2 * WJ];
      const float4 wb = *(const float4*)&w1p[kk * 2 * WJ];
      const float xl[4] = {xlo4.x, xlo4.y, xlo4.z, xlo4.w};
      const float xh[4] = {xhi4.x, xhi4.y, xhi4.z, xhi4.w};
      const float wv[8] = {wa.x, wa.y, wa.z, wa.w, wb.x, wb.y, wb.z, wb.w};
#pragma unroll
      for (int rr = 0; rr < 4; ++rr)
#pragma unroll
        for (int jj = 0; jj < 8; ++jj) {
          acc[rr][jj]     += xl[rr] * wv[jj];
          acc[rr + 4][jj] += xh[rr] * wv[jj];
        }
    }
  };

  auto reduce = [&]() {
#pragma unroll
    for (int rr = 0; rr < 8; ++rr)
#pragma unroll
      for (int jj = 0; jj < 8; ++jj)
        acc[rr][jj] += __shfl_xor(acc[rr][jj], 32, 64);
  };

  const int eb = (r0 + 4 * ksb) ^ ((colg & 1) << 2);  // swizzled row base for epi

  for (int bk = 0; bk < NB; ++bk) {
    const float* wa = wpadA + (size_t)bk * (WID * WJ);
    const float* wb = wpadB + (size_t)bk * (WID * WJ);

    // ---------------- GEMM1: v = 2*relu(2*((x+b1)@Wa) + b2) + b3 ----------
    __syncthreads();                 // wbuf free; xsT stable
    write_stage();                   // Wa rows 0..49
    issue_stage(wa + 50 * WJ);       // prefetch Wa rows 50..99
    __syncthreads();
    zero_acc();
    kloop(xsT, 0);
    __syncthreads();
    write_stage();                   // Wa rows 50..99
    issue_stage(wb);                 // prefetch Wb rows 0..49
    __syncthreads();
    kloop(xsT, 50);
    reduce();
    {
      const float b1 = B1[bk], b2 = B2[bk], b3 = B3[bk];
      const float4 cs0 = *(const float4*)&csA[bk * WJ + j0];
      const float4 cs1 = *(const float4*)&csA[bk * WJ + j0 + 4];
      const float cs[8] = {cs0.x, cs0.y, cs0.z, cs0.w, cs1.x, cs1.y, cs1.z, cs1.w};
      auto vf = [&](float a, float c) {
        return 2.0f * fmaxf(2.0f * (a + b1 * c) + b2, 0.0f) + b3;
      };
      if (ksb == 0) {
#pragma unroll
        for (int jj = 0; jj < 8; ++jj) {
          if (j0 + jj < WID) {
            float4 o = make_float4(vf(acc[0][jj], cs[jj]), vf(acc[1][jj], cs[jj]),
                                   vf(acc[2][jj], cs[jj]), vf(acc[3][jj], cs[jj]));
            *(float4*)&vsT[(j0 + jj) * 64 + eb] = o;
          }
        }
      } else {
#pragma unroll
        for (int jj = 0; jj < 8; ++jj) {
          if (j0 + jj < WID) {
            float4 o = make_float4(vf(acc[4][jj], cs[jj]), vf(acc[5][jj], cs[jj]),
                                   vf(acc[6][jj], cs[jj]), vf(acc[7][jj], cs[jj]));
            *(float4*)&vsT[(j0 + jj) * 64 + eb] = o;
          }
        }
      }
    }

    // ---------------- GEMM2: x = relu(x + (v@Wb)*m + b4) -------------------
    __syncthreads();                 // wbuf free (kloop done); vsT written
    write_stage();                   // Wb rows 0..49
    issue_stage(wb + 50 * WJ);       // prefetch Wb rows 50..99
    __syncthreads();
    zero_acc();
    kloop(vsT, 0);
    __syncthreads();
    write_stage();                   // Wb rows 50..99
    {
      const float* nwa = wpadA + (size_t)((bk + 1 < NB) ? bk + 1 : bk) * (WID * WJ);
      issue_stage(nwa);              // prefetch next block's Wa rows 0..49
    }
    __syncthreads();
    kloop(vsT, 50);
    reduce();
    {
      const float b4v = B4[bk], mv = M[bk];
      if (ksb == 0) {
#pragma unroll
        for (int jj = 0; jj < 8; ++jj) {
          if (j0 + jj < WID) {
            float* p = &xsT[(j0 + jj) * 64 + eb];
            float4 xo = *(const float4*)p;
            float4 xn = make_float4(fmaxf(xo.x + acc[0][jj] * mv + b4v, 0.0f),
                                    fmaxf(xo.y + acc[1][jj] * mv + b4v, 0.0f),
                                    fmaxf(xo.z + acc[2][jj] * mv + b4v, 0.0f),
                                    fmaxf(xo.w + acc[3][jj] * mv + b4v, 0.0f));
            *(float4*)p = xn;
          }
        }
      } else {
#pragma unroll
        for (int jj = 0; jj < 8; ++jj) {
          if (j0 + jj < WID) {
            float* p = &xsT[(j0 + jj) * 64 + eb];
            float4 xo = *(const float4*)p;
            float4 xn = make_float4(fmaxf(xo.x + acc[4][jj] * mv + b4v, 0.0f),
                                    fmaxf(xo.y + acc[5][jj] * mv + b4v, 0.0f),
                                    fmaxf(xo.z + acc[6][jj] * mv + b4v, 0.0f),
                                    fmaxf(xo.w + acc[7][jj] * mv + b4v, 0.0f));
            *(float4*)p = xn;
          }
        }
      }
    }
  }

  __syncthreads();
  for (int i = tid; i < RPW * WID; i += 256) {
    const int k = i >> 6, r = i & 63;
    const int sw = ((k >> 3) & 1) << 2;
    x0[(size_t)(rbase + r) * WID + k] = xsT[k * 64 + (r ^ sw)];
  }
}

// ---------------------------------------------------------------------------
// Output head + stencil epilogue. One block per batch image (16x16 grid).
// ---------------------------------------------------------------------------
__global__ __launch_bounds__(256) void out_kernel(
    const float* __restrict__ inp, const float* __restrict__ x0,
    const float* __restrict__ Wout, const float* __restrict__ bout,
    float* __restrict__ out) {
  __shared__ float ys[256 * 4];
  __shared__ float wouts[WID * 4];
  __shared__ float bos[4];
  const int tid = threadIdx.x;
  const int b   = blockIdx.x;

  for (int i = tid; i < WID * 4; i += 256) wouts[i] = Wout[i];
  if (tid < 4) bos[tid] = bout[tid];
  __syncthreads();

  const int row = b * 256 + tid;
  const float* xr = x0 + (size_t)row * WID;
  float a0 = 0.f, a1 = 0.f, a2 = 0.f, a3 = 0.f;
#pragma unroll 4
  for (int k = 0; k < WID; ++k) {
    const float xv = xr[k];
    a0 += xv * wouts[k * 4 + 0];
    a1 += xv * wouts[k * 4 + 1];
    a2 += xv * wouts[k * 4 + 2];
    a3 += xv * wouts[k * 4 + 3];
  }
  ys[tid * 4 + 0] = a0 + bos[0];
  ys[tid * 4 + 1] = a1 + bos[1];
  ys[tid * 4 + 2] = a2 + bos[2];
  ys[tid * 4 + 3] = a3 + bos[3];
  __syncthreads();

  const int i = tid >> 4, j = tid & 15;
  const int ip1 = (i + 1) & 15, im1 = (i + 15) & 15;
  const int jp1 = (j + 1) & 15, jm1 = (j + 15) & 15;
  auto Y = [&](int a, int c, int comp) { return ys[(((a << 4) | c) << 2) + comp]; };
  const float y0 = Y(i, j, 0), y1 = Y(i, j, 1), y2 = Y(i, j, 2), y3 = Y(i, j, 3);
  const float right_c = y0 / (Y(ip1, j, 1) + y0);
  const float left_c  = y1 / (y1 + Y(im1, j, 0));
  const float up_c    = y2 / (y2 + Y(i, jp1, 3));
  const float down_c  = y3 / (Y(i, jm1, 2) + y3);

  const float* base = inp + (size_t)b * (32 * 32 * 9);
  const int g1 = 2 * i + 1, g1m = (2 * i + 31) & 31;
  const int g2 = 2 * j + 1, g2m = (2 * j + 31) & 31;
  const float* oo = base + (g1 * 32 + g2) * 9;
  const float* oi = base + (g1 * 32 + g2m) * 9;
  const float* io = base + (g1m * 32 + g2) * 9;
  const float* ii = base + (g1m * 32 + g2m) * 9;
  const float ru = -(oo[0] + oo[3] * right_c + oo[1] * up_c) / oo[4];
  const float rd = -(oi[2] + oi[5] * right_c + oi[1] * down_c) / oi[4];
  const float lu = -(io[6] + io[3] * left_c + io[7] * up_c) / io[4];
  const float ld = -(ii[8] + ii[5] * left_c + ii[7] * down_c) / ii[4];

  float* o = out + (size_t)row * 9;
  o[0] = ld;     o[1] = left_c;  o[2] = lu;
  o[3] = down_c; o[4] = 1.0f;    o[5] = up_c;
  o[6] = rd;     o[7] = right_c; o[8] = ru;
}

// ---------------------------------------------------------------------------
extern "C" void kernel_launch(void* const* d_in, const int* in_sizes, int n_in,
                              void* d_out, int out_size, void* d_ws, size_t ws_size,
                              hipStream_t stream) {
  const float* inp  = (const float*)d_in[0];
  const float* W0   = (const float*)d_in[1];
  const float* Wa   = (const float*)d_in[2];
  const float* Wb   = (const float*)d_in[3];
  const float* B1   = (const float*)d_in[4];
  const float* B2   = (const float*)d_in[5];
  const float* B3   = (const float*)d_in[6];
  const float* B4   = (const float*)d_in[7];
  const float* M    = (const float*)d_in[8];
  const float* Wout = (const float*)d_in[9];
  const float* bout = (const float*)d_in[10];
  float* out = (float*)d_out;

  float* ws    = (float*)d_ws;
  float* x0    = ws;                          // 32768*100       = 3,276,800 floats
  float* wpadA = ws + 3276800;                // 50*100*128      =   640,000
  float* wpadB = wpadA + 640000;              //                 =   640,000
  float* csA   = wpadB + 640000;              // 50*128          =     6,400

  hipLaunchKernelGGL(prep_kernel, dim3(100), dim3(256), 0, stream,
                     Wa, Wb, wpadA, wpadB, csA);
  hipLaunchKernelGGL(first_layer_kernel, dim3(ROWS / 64), dim3(256), 0, stream,
                     inp, W0, x0);
  hipLaunchKernelGGL(chain_kernel, dim3(ROWS / RPW), dim3(256), 0, stream,
                     x0, wpadA, wpadB, csA, B1, B2, B3, B4, M);
  hipLaunchKernelGGL(out_kernel, dim3(BATCH), dim3(256), 0, stream,
                     inp, x0, Wout, bout, out);
}

// Round 3
// 1991.805 us; speedup vs baseline: 2.2834x; 2.2834x over previous
//
#include <hip/hip_runtime.h>
#include <cstddef>

// Problem constants
constexpr int BATCH = 128;
constexpr int T     = 16;             // coarse grid
constexpr int ROWS  = BATCH * T * T;  // 32768
constexpr int WID   = 100;            // network width
constexpr int NB    = 50;             // residual blocks
constexpr int JT    = 28;             // j-tile per wave (4 waves x 28 = 112 >= 100)
constexpr int XS    = 128;            // LDS row stride in dwords (pow2 for XOR swizzle)
constexpr int RPW   = 64;             // rows per workgroup in chain kernel

// ---------------------------------------------------------------------------
// Prep: re-layout weights [50][100][100] -> [50][4 waves][100][28] contiguous
// per-(block,wave) chunks (zero-padded j>=100) so the chain kernel's
// wave-uniform weight reads scalarize into s_load_dwordx8/16.
// Also per-(block,wave) column sums of Wa (b1 scalar-bias fold).
// ---------------------------------------------------------------------------
__global__ __launch_bounds__(256) void prep_kernel(
    const float* __restrict__ Wa, const float* __restrict__ Wb,
    float* __restrict__ wpA, float* __restrict__ wpB,
    float* __restrict__ csw) {
  const int bid = blockIdx.x;          // 0..99
  const int bk  = bid % NB;
  const bool isA = bid < NB;
  const float* src = (isA ? Wa : Wb) + (size_t)bk * (WID * WID);
  float* dst = (isA ? wpA : wpB) + (size_t)bk * (4 * WID * JT);
  for (int i = threadIdx.x; i < 4 * WID * JT; i += 256) {
    const int w   = i / (WID * JT);
    const int rem = i - w * (WID * JT);
    const int k   = rem / JT;
    const int jj  = rem - k * JT;
    const int j   = w * JT + jj;
    dst[i] = (j < WID) ? src[k * WID + j] : 0.0f;
  }
  if (isA) {
    for (int jt = threadIdx.x; jt < 4 * JT; jt += 256) {
      const int j = jt;                // jt == w*JT + jj == global padded j
      float s = 0.0f;
      if (j < WID) {
        for (int k = 0; k < WID; ++k) s += src[k * WID + j];
      }
      csw[bk * (4 * JT) + jt] = s;
    }
  }
}

// ---------------------------------------------------------------------------
// First layer: gather 45-wide stencil rows, x0 = relu(flat @ W0)
// ---------------------------------------------------------------------------
__global__ __launch_bounds__(256) void first_layer_kernel(
    const float* __restrict__ inp, const float* __restrict__ W0,
    float* __restrict__ x0) {
  __shared__ float w0s[45 * WID];
  for (int i = threadIdx.x; i < 45 * WID; i += 256) w0s[i] = W0[i];
  __syncthreads();

  const int rq  = threadIdx.x >> 2;   // 0..63
  const int cq  = threadIdx.x & 3;    // 0..3
  const int row = blockIdx.x * 64 + rq;
  const int b   = row >> 8;
  const int t1  = (row >> 4) & 15;
  const int t2  = row & 15;
  const int g1  = 2 * t1, g2 = 2 * t2;
  const int g1m = (g1 + 31) & 31, g2m = (g2 + 31) & 31;
  const float* base = inp + (size_t)b * (32 * 32 * 9);
  const float* p0 = base + ((g1 + 1) * 32 + g2) * 9;
  const float* p1 = base + (g1m * 32 + g2) * 9;
  const float* p2 = base + (g1 * 32 + (g2 + 1)) * 9;
  const float* p3 = base + (g1 * 32 + g2m) * 9;
  const float* p4 = base + (g1 * 32 + g2) * 9;

  float f[45];
#pragma unroll
  for (int q = 0; q < 9; ++q) {
    f[q]      = p0[q];
    f[9 + q]  = p1[q];
    f[18 + q] = p2[q];
    f[27 + q] = p3[q];
    f[36 + q] = p4[q];
  }

  float acc[25];
#pragma unroll
  for (int j = 0; j < 25; ++j) acc[j] = 0.0f;
  const int j0 = cq * 25;
#pragma unroll
  for (int k = 0; k < 45; ++k) {
    const float fv = f[k];
#pragma unroll
    for (int j = 0; j < 25; ++j) acc[j] += fv * w0s[k * WID + j0 + j];
  }
  float* orow = x0 + (size_t)row * WID + j0;
#pragma unroll
  for (int j = 0; j < 25; ++j) orow[j] = fmaxf(acc[j], 0.0f);
}

// ---------------------------------------------------------------------------
// Chain: 50 residual blocks fused. 512 WGs x 256 threads, 64 rows/WG.
// Lane = one row; wave = one 28-col j-tile; weights via wave-uniform s_load
// (SGPR operand of v_fmac) -> 1 ds_read_b128 per 112 FMAs, 2 barriers/block.
// LDS rows XOR-swizzled: element (r,c) at r*128 + (c ^ ((r&7)<<2)).
// ---------------------------------------------------------------------------
__global__ __launch_bounds__(256, 2) void chain_kernel(
    float* __restrict__ x0,
    const float* __restrict__ wpA, const float* __restrict__ wpB,
    const float* __restrict__ csw,
    const float* __restrict__ B1, const float* __restrict__ B2,
    const float* __restrict__ B3, const float* __restrict__ B4,
    const float* __restrict__ M) {
  __shared__ __align__(16) float xs[RPW * XS];   // 32768 B
  __shared__ __align__(16) float vs[RPW * XS];   // 32768 B

  const int tid   = threadIdx.x;
  const int lane  = tid & 63;
  const int uw    = __builtin_amdgcn_readfirstlane(tid >> 6);  // wave 0..3
  const int r     = lane;                                      // row 0..63
  const int rbase = blockIdx.x * RPW;
  const int sw    = (r & 7) << 2;                              // XOR swizzle
  const int j0    = uw * JT;

  // load x tile (global coalesced -> swizzled LDS)
  for (int i = tid; i < RPW * WID; i += 256) {
    const int rr = i / WID, c = i - rr * WID;
    xs[rr * XS + (c ^ ((rr & 7) << 2))] = x0[(size_t)rbase * WID + i];
  }
  __syncthreads();

  float acc[JT];
  const float* xrow = &xs[r * XS];
  const float* vrow = &vs[r * XS];

  for (int bk = 0; bk < NB; ++bk) {
    const float* wa = wpA + (size_t)(bk * 4 + uw) * (WID * JT);
    const float* wb = wpB + (size_t)(bk * 4 + uw) * (WID * JT);
    const float* cs = csw + (bk * 4 + uw) * JT;
    const float b1 = B1[bk], b2 = B2[bk], b3 = B3[bk], b4 = B4[bk], mm = M[bk];

    // ---------------- GEMM1: acc = x @ Wa (j-tile) ------------------------
#pragma unroll
    for (int j = 0; j < JT; ++j) acc[j] = 0.0f;
#pragma unroll 5
    for (int g = 0; g < 25; ++g) {
      const float4 xv = *(const float4*)&xrow[(4 * g) ^ sw];
#pragma unroll
      for (int kk = 0; kk < 4; ++kk) {
        const float xk = (&xv.x)[kk];
        const float* wr = wa + (4 * g + kk) * JT;    // wave-uniform -> s_load
#pragma unroll
        for (int j = 0; j < JT; ++j) acc[j] = fmaf(xk, wr[j], acc[j]);
      }
    }
    // epilogue1: v = 2*relu(2*(acc + b1*colsum) + b2) + b3 -> vs
#pragma unroll
    for (int m4 = 0; m4 < JT / 4; ++m4) {
      float4 o;
#pragma unroll
      for (int q = 0; q < 4; ++q) {
        const int j = 4 * m4 + q;
        const float t = 2.0f * (acc[j] + b1 * cs[j]) + b2;
        (&o.x)[q] = 2.0f * fmaxf(t, 0.0f) + b3;
      }
      *(float4*)&vs[r * XS + ((j0 + 4 * m4) ^ sw)] = o;
    }
    __syncthreads();

    // ---------------- GEMM2: acc = v @ Wb (j-tile) ------------------------
#pragma unroll
    for (int j = 0; j < JT; ++j) acc[j] = 0.0f;
#pragma unroll 5
    for (int g = 0; g < 25; ++g) {
      const float4 xv = *(const float4*)&vrow[(4 * g) ^ sw];
#pragma unroll
      for (int kk = 0; kk < 4; ++kk) {
        const float xk = (&xv.x)[kk];
        const float* wr = wb + (4 * g + kk) * JT;    // wave-uniform -> s_load
#pragma unroll
        for (int j = 0; j < JT; ++j) acc[j] = fmaf(xk, wr[j], acc[j]);
      }
    }
    // epilogue2: x = relu(x + acc*m + b4) in place in xs
#pragma unroll
    for (int m4 = 0; m4 < JT / 4; ++m4) {
      float* p = &xs[r * XS + ((j0 + 4 * m4) ^ sw)];
      const float4 xo = *(const float4*)p;
      float4 xn;
#pragma unroll
      for (int q = 0; q < 4; ++q)
        (&xn.x)[q] = fmaxf((&xo.x)[q] + acc[4 * m4 + q] * mm + b4, 0.0f);
      *(float4*)p = xn;
    }
    __syncthreads();
  }

  // write back
  for (int i = tid; i < RPW * WID; i += 256) {
    const int rr = i / WID, c = i - rr * WID;
    x0[(size_t)rbase * WID + i] = xs[rr * XS + (c ^ ((rr & 7) << 2))];
  }
}

// ---------------------------------------------------------------------------
// Output head + stencil epilogue. One block per batch image (16x16 grid).
// ---------------------------------------------------------------------------
__global__ __launch_bounds__(256) void out_kernel(
    const float* __restrict__ inp, const float* __restrict__ x0,
    const float* __restrict__ Wout, const float* __restrict__ bout,
    float* __restrict__ out) {
  __shared__ float ys[256 * 4];
  __shared__ float wouts[WID * 4];
  __shared__ float bos[4];
  const int tid = threadIdx.x;
  const int b   = blockIdx.x;

  for (int i = tid; i < WID * 4; i += 256) wouts[i] = Wout[i];
  if (tid < 4) bos[tid] = bout[tid];
  __syncthreads();

  const int row = b * 256 + tid;
  const float* xr = x0 + (size_t)row * WID;
  float a0 = 0.f, a1 = 0.f, a2 = 0.f, a3 = 0.f;
#pragma unroll 4
  for (int k = 0; k < WID; ++k) {
    const float xv = xr[k];
    a0 += xv * wouts[k * 4 + 0];
    a1 += xv * wouts[k * 4 + 1];
    a2 += xv * wouts[k * 4 + 2];
    a3 += xv * wouts[k * 4 + 3];
  }
  ys[tid * 4 + 0] = a0 + bos[0];
  ys[tid * 4 + 1] = a1 + bos[1];
  ys[tid * 4 + 2] = a2 + bos[2];
  ys[tid * 4 + 3] = a3 + bos[3];
  __syncthreads();

  const int i = tid >> 4, j = tid & 15;
  const int ip1 = (i + 1) & 15, im1 = (i + 15) & 15;
  const int jp1 = (j + 1) & 15, jm1 = (j + 15) & 15;
  auto Y = [&](int a, int c, int comp) { return ys[(((a << 4) | c) << 2) + comp]; };
  const float y0 = Y(i, j, 0), y1 = Y(i, j, 1), y2 = Y(i, j, 2), y3 = Y(i, j, 3);
  const float right_c = y0 / (Y(ip1, j, 1) + y0);
  const float left_c  = y1 / (y1 + Y(im1, j, 0));
  const float up_c    = y2 / (y2 + Y(i, jp1, 3));
  const float down_c  = y3 / (Y(i, jm1, 2) + y3);

  const float* base = inp + (size_t)b * (32 * 32 * 9);
  const int g1 = 2 * i + 1, g1m = (2 * i + 31) & 31;
  const int g2 = 2 * j + 1, g2m = (2 * j + 31) & 31;
  const float* oo = base + (g1 * 32 + g2) * 9;
  const float* oi = base + (g1 * 32 + g2m) * 9;
  const float* io = base + (g1m * 32 + g2) * 9;
  const float* ii = base + (g1m * 32 + g2m) * 9;
  const float ru = -(oo[0] + oo[3] * right_c + oo[1] * up_c) / oo[4];
  const float rd = -(oi[2] + oi[5] * right_c + oi[1] * down_c) / oi[4];
  const float lu = -(io[6] + io[3] * left_c + io[7] * up_c) / io[4];
  const float ld = -(ii[8] + ii[5] * left_c + ii[7] * down_c) / ii[4];

  float* o = out + (size_t)row * 9;
  o[0] = ld;     o[1] = left_c;  o[2] = lu;
  o[3] = down_c; o[4] = 1.0f;    o[5] = up_c;
  o[6] = rd;     o[7] = right_c; o[8] = ru;
}

// ---------------------------------------------------------------------------
extern "C" void kernel_launch(void* const* d_in, const int* in_sizes, int n_in,
                              void* d_out, int out_size, void* d_ws, size_t ws_size,
                              hipStream_t stream) {
  const float* inp  = (const float*)d_in[0];
  const float* W0   = (const float*)d_in[1];
  const float* Wa   = (const float*)d_in[2];
  const float* Wb   = (const float*)d_in[3];
  const float* B1   = (const float*)d_in[4];
  const float* B2   = (const float*)d_in[5];
  const float* B3   = (const float*)d_in[6];
  const float* B4   = (const float*)d_in[7];
  const float* M    = (const float*)d_in[8];
  const float* Wout = (const float*)d_in[9];
  const float* bout = (const float*)d_in[10];
  float* out = (float*)d_out;

  float* ws  = (float*)d_ws;
  float* x0  = ws;                        // 32768*100        = 3,276,800 floats
  float* wpA = ws + 3276800;              // 50*4*100*28      =   560,000
  float* wpB = wpA + 560000;              //                  =   560,000
  float* csw = wpB + 560000;              // 50*4*28          =     5,600

  hipLaunchKernelGGL(prep_kernel, dim3(100), dim3(256), 0, stream,
                     Wa, Wb, wpA, wpB, csw);
  hipLaunchKernelGGL(first_layer_kernel, dim3(ROWS / 64), dim3(256), 0, stream,
                     inp, W0, x0);
  hipLaunchKernelGGL(chain_kernel, dim3(ROWS / RPW), dim3(256), 0, stream,
                     x0, wpA, wpB, csw, B1, B2, B3, B4, M);
  hipLaunchKernelGGL(out_kernel, dim3(BATCH), dim3(256), 0, stream,
                     inp, x0, Wout, bout, out);
}

// Round 5
// 418.347 us; speedup vs baseline: 10.8717x; 4.7611x over previous
//
#include <hip/hip_runtime.h>
#include <cstddef>

typedef _Float16 f16x8 __attribute__((ext_vector_type(8)));
typedef float f32x4 __attribute__((ext_vector_type(4)));

// Problem constants
constexpr int BATCH = 128;
constexpr int T     = 16;
constexpr int ROWS  = BATCH * T * T;  // 32768
constexpr int WID   = 100;
constexpr int NB    = 50;
constexpr int KP    = 128;            // padded K (4 MFMA k-steps of 32)
constexpr int NP    = 128;            // padded N (8 col-tiles of 16)
constexpr int RPW   = 64;             // rows per workgroup
constexpr int WCH   = 16384;          // f16 elements per fragment-imaged matrix

// ---------------------------------------------------------------------------
// Prep: split weights into f16 hi/lo pairs (w = hi + lo, lo = w - (f16)w) in
// MFMA B-fragment stream order. Chunk (bk,m,kap,tau) is 1KB: lane L, elem i ->
// W[k=32*kap+(L>>4)*8+i][col=16*tau+(L&15)], zero-padded outside 100x100.
// Also colsum of Wa for the b1 scalar-bias fold.
// ---------------------------------------------------------------------------
__global__ __launch_bounds__(256) void prep_kernel(
    const float* __restrict__ Wa, const float* __restrict__ Wb,
    _Float16* __restrict__ whi, _Float16* __restrict__ wlo,
    float* __restrict__ csA) {
  const int bid = blockIdx.x;          // 0..99 = bk*2 + m
  const int bk = bid >> 1, m = bid & 1;
  const float* src = (m ? Wb : Wa) + (size_t)bk * (WID * WID);
  _Float16* dh = whi + (size_t)bid * WCH;
  _Float16* dl = wlo + (size_t)bid * WCH;
  for (int e = threadIdx.x; e < WCH; e += 256) {
    const int i   = e & 7;
    const int L   = (e >> 3) & 63;
    const int tau = (e >> 9) & 7;
    const int kap = e >> 12;
    const int k   = 32 * kap + (L >> 4) * 8 + i;
    const int col = 16 * tau + (L & 15);
    const float v = (k < WID && col < WID) ? src[k * WID + col] : 0.0f;
    const _Float16 hi = (_Float16)v;
    dh[e] = hi;
    dl[e] = (_Float16)(v - (float)hi);
  }
  if (!m) {
    for (int col = threadIdx.x; col < NP; col += 256) {
      float s = 0.0f;
      if (col < WID) {
        for (int k = 0; k < WID; ++k) s += src[k * WID + col];
      }
      csA[bk * NP + col] = s;
    }
  }
}

// ---------------------------------------------------------------------------
// First layer: gather 45-wide stencil rows, x0 = relu(flat @ W0)
// ---------------------------------------------------------------------------
__global__ __launch_bounds__(256) void first_layer_kernel(
    const float* __restrict__ inp, const float* __restrict__ W0,
    float* __restrict__ x0) {
  __shared__ float w0s[45 * WID];
  for (int i = threadIdx.x; i < 45 * WID; i += 256) w0s[i] = W0[i];
  __syncthreads();

  const int rq  = threadIdx.x >> 2;
  const int cq  = threadIdx.x & 3;
  const int row = blockIdx.x * 64 + rq;
  const int b   = row >> 8;
  const int t1  = (row >> 4) & 15;
  const int t2  = row & 15;
  const int g1  = 2 * t1, g2 = 2 * t2;
  const int g1m = (g1 + 31) & 31, g2m = (g2 + 31) & 31;
  const float* base = inp + (size_t)b * (32 * 32 * 9);
  const float* p0 = base + ((g1 + 1) * 32 + g2) * 9;
  const float* p1 = base + (g1m * 32 + g2) * 9;
  const float* p2 = base + (g1 * 32 + (g2 + 1)) * 9;
  const float* p3 = base + (g1 * 32 + g2m) * 9;
  const float* p4 = base + (g1 * 32 + g2) * 9;

  float f[45];
#pragma unroll
  for (int qq = 0; qq < 9; ++qq) {
    f[qq]      = p0[qq];
    f[9 + qq]  = p1[qq];
    f[18 + qq] = p2[qq];
    f[27 + qq] = p3[qq];
    f[36 + qq] = p4[qq];
  }

  float acc[25];
#pragma unroll
  for (int j = 0; j < 25; ++j) acc[j] = 0.0f;
  const int j0 = cq * 25;
#pragma unroll
  for (int k = 0; k < 45; ++k) {
    const float fv = f[k];
#pragma unroll
    for (int j = 0; j < 25; ++j) acc[j] += fv * w0s[k * WID + j0 + j];
  }
  float* orow = x0 + (size_t)row * WID + j0;
#pragma unroll
  for (int j = 0; j < 25; ++j) orow[j] = fmaxf(acc[j], 0.0f);
}

// ---------------------------------------------------------------------------
// Chain: 50 residual blocks, split-f16 MFMA (f32 accum, error ~2^-22).
// 512 WGs x 256 thr. LDS: x hi/lo + v hi/lo, each f16 [64][128] XOR-swizzled
// (k ^ ((row&7)<<3)). Weights read global->VGPR directly (per-wave-owned
// fragment chunks, coalesced 16B/lane). fp32 residual state in registers.
// Per GEMM per wave: 16 B-loads(global), 32 A-reads(ds b128), 96 MFMA.
// ---------------------------------------------------------------------------
__global__ __launch_bounds__(256, 2) void chain_kernel(
    float* __restrict__ x0,
    const _Float16* __restrict__ whi, const _Float16* __restrict__ wlo,
    const float* __restrict__ csA,
    const float* __restrict__ B1, const float* __restrict__ B2,
    const float* __restrict__ B3, const float* __restrict__ B4,
    const float* __restrict__ M) {
  __shared__ __align__(16) _Float16 xhs[RPW * KP];   // 16 KB
  __shared__ __align__(16) _Float16 xls[RPW * KP];   // 16 KB
  __shared__ __align__(16) _Float16 vhs[RPW * KP];   // 16 KB
  __shared__ __align__(16) _Float16 vls[RPW * KP];   // 16 KB

  const int tid  = threadIdx.x;
  const int lane = tid & 63;
  const int uw   = __builtin_amdgcn_readfirstlane(tid >> 6);  // wave 0..3
  const int q    = lane >> 4;   // 0..3
  const int fr   = lane & 15;   // 0..15
  const int rbase = blockIdx.x * RPW;

  // fill x hi/lo (f32 -> split f16, swizzled)
  for (int i = tid; i < RPW * KP; i += 256) {
    const int row = i >> 7, k = i & 127;
    const float v = (k < WID) ? x0[(size_t)(rbase + row) * WID + k] : 0.0f;
    const _Float16 hi = (_Float16)v;
    const int a = row * KP + (k ^ ((row & 7) << 3));
    xhs[a] = hi;
    xls[a] = (_Float16)(v - (float)hi);
  }

  // fp32 residual state: 4 row-tiles x 2 col-tiles x 4 regs
  int colc[2];
#pragma unroll
  for (int c = 0; c < 2; ++c) colc[c] = 16 * (2 * uw + c) + fr;
  float xres[4][2][4];
#pragma unroll
  for (int rt = 0; rt < 4; ++rt)
#pragma unroll
    for (int c = 0; c < 2; ++c)
#pragma unroll
      for (int rg = 0; rg < 4; ++rg) {
        const int row = 16 * rt + 4 * q + rg;
        xres[rt][c][rg] = (colc[c] < WID)
            ? x0[(size_t)(rbase + row) * WID + colc[c]] : 0.0f;
      }
  __syncthreads();

  f32x4 acc[4][2];
  auto zero_acc = [&]() {
#pragma unroll
    for (int rt = 0; rt < 4; ++rt)
#pragma unroll
      for (int c = 0; c < 2; ++c) acc[rt][c] = (f32x4){0.f, 0.f, 0.f, 0.f};
  };

  // split-f16 GEMM: acc += (ah+al) @ (bh+bl), dropping al*bl (~2^-22)
  auto kloop = [&](const _Float16* __restrict__ gh,
                   const _Float16* __restrict__ gl,
                   const _Float16* ah_s, const _Float16* al_s) {
    f16x8 bh[4][2], bl[4][2];
#pragma unroll
    for (int kap = 0; kap < 4; ++kap)
#pragma unroll
      for (int c = 0; c < 2; ++c) {
        const int off = (kap * 8 + 2 * uw + c) * 512 + lane * 8;
        bh[kap][c] = *(const f16x8*)&gh[off];
        bl[kap][c] = *(const f16x8*)&gl[off];
      }
#pragma unroll
    for (int kap = 0; kap < 4; ++kap) {
      f16x8 ah[4], al[4];
#pragma unroll
      for (int rt = 0; rt < 4; ++rt) {
        const int row = 16 * rt + fr;
        const int off = row * KP + ((32 * kap + 8 * q) ^ ((fr & 7) << 3));
        ah[rt] = *(const f16x8*)&ah_s[off];
        al[rt] = *(const f16x8*)&al_s[off];
      }
#pragma unroll
      for (int rt = 0; rt < 4; ++rt)
#pragma unroll
        for (int c = 0; c < 2; ++c) {
          acc[rt][c] = __builtin_amdgcn_mfma_f32_16x16x32_f16(
              ah[rt], bh[kap][c], acc[rt][c], 0, 0, 0);
          acc[rt][c] = __builtin_amdgcn_mfma_f32_16x16x32_f16(
              ah[rt], bl[kap][c], acc[rt][c], 0, 0, 0);
          acc[rt][c] = __builtin_amdgcn_mfma_f32_16x16x32_f16(
              al[rt], bh[kap][c], acc[rt][c], 0, 0, 0);
        }
    }
  };

  for (int bk = 0; bk < NB; ++bk) {
    // ---------------- GEMM1: v = 2*relu(2*((x+b1)@Wa) + b2) + b3 ----------
    zero_acc();
    kloop(whi + (size_t)(bk * 2) * WCH, wlo + (size_t)(bk * 2) * WCH, xhs, xls);
    {
      const float b1 = B1[bk], b2 = B2[bk], b3 = B3[bk];
      const float csv[2] = {csA[bk * NP + colc[0]], csA[bk * NP + colc[1]]};
#pragma unroll
      for (int rt = 0; rt < 4; ++rt)
#pragma unroll
        for (int c = 0; c < 2; ++c)
#pragma unroll
          for (int rg = 0; rg < 4; ++rg) {
            const int row = 16 * rt + 4 * q + rg;
            const float t = 2.0f * (acc[rt][c][rg] + b1 * csv[c]) + b2;
            const float v = 2.0f * fmaxf(t, 0.0f) + b3;
            const _Float16 hi = (_Float16)v;
            const int a = row * KP + (colc[c] ^ ((row & 7) << 3));
            vhs[a] = hi;
            vls[a] = (_Float16)(v - (float)hi);
          }
    }
    __syncthreads();            // publish v

    // ---------------- GEMM2: x = relu(x + (v@Wb)*m + b4) -------------------
    zero_acc();
    kloop(whi + (size_t)(bk * 2 + 1) * WCH, wlo + (size_t)(bk * 2 + 1) * WCH,
          vhs, vls);
    {
      const float b4v = B4[bk], mm = M[bk];
#pragma unroll
      for (int rt = 0; rt < 4; ++rt)
#pragma unroll
        for (int c = 0; c < 2; ++c)
#pragma unroll
          for (int rg = 0; rg < 4; ++rg) {
            const int row = 16 * rt + 4 * q + rg;
            const float xn = fmaxf(xres[rt][c][rg] + acc[rt][c][rg] * mm + b4v, 0.0f);
            xres[rt][c][rg] = xn;
            const _Float16 hi = (_Float16)xn;
            const int a = row * KP + (colc[c] ^ ((row & 7) << 3));
            xhs[a] = hi;
            xls[a] = (_Float16)(xn - (float)hi);
          }
    }
    __syncthreads();            // publish x(bk+1)
  }

  // write back fp32 residual state
#pragma unroll
  for (int rt = 0; rt < 4; ++rt)
#pragma unroll
    for (int c = 0; c < 2; ++c)
#pragma unroll
      for (int rg = 0; rg < 4; ++rg) {
        const int row = 16 * rt + 4 * q + rg;
        if (colc[c] < WID)
          x0[(size_t)(rbase + row) * WID + colc[c]] = xres[rt][c][rg];
      }
}

// ---------------------------------------------------------------------------
// Output head + stencil epilogue. One block per batch image (16x16 grid).
// ---------------------------------------------------------------------------
__global__ __launch_bounds__(256) void out_kernel(
    const float* __restrict__ inp, const float* __restrict__ x0,
    const float* __restrict__ Wout, const float* __restrict__ bout,
    float* __restrict__ out) {
  __shared__ float ys[256 * 4];
  __shared__ float wouts[WID * 4];
  __shared__ float bos[4];
  const int tid = threadIdx.x;
  const int b   = blockIdx.x;

  for (int i = tid; i < WID * 4; i += 256) wouts[i] = Wout[i];
  if (tid < 4) bos[tid] = bout[tid];
  __syncthreads();

  const int row = b * 256 + tid;
  const float* xr = x0 + (size_t)row * WID;
  float a0 = 0.f, a1 = 0.f, a2 = 0.f, a3 = 0.f;
#pragma unroll 4
  for (int k = 0; k < WID; ++k) {
    const float xv = xr[k];
    a0 += xv * wouts[k * 4 + 0];
    a1 += xv * wouts[k * 4 + 1];
    a2 += xv * wouts[k * 4 + 2];
    a3 += xv * wouts[k * 4 + 3];
  }
  ys[tid * 4 + 0] = a0 + bos[0];
  ys[tid * 4 + 1] = a1 + bos[1];
  ys[tid * 4 + 2] = a2 + bos[2];
  ys[tid * 4 + 3] = a3 + bos[3];
  __syncthreads();

  const int i = tid >> 4, j = tid & 15;
  const int ip1 = (i + 1) & 15, im1 = (i + 15) & 15;
  const int jp1 = (j + 1) & 15, jm1 = (j + 15) & 15;
  auto Y = [&](int a, int c, int comp) { return ys[(((a << 4) | c) << 2) + comp]; };
  const float y0 = Y(i, j, 0), y1 = Y(i, j, 1), y2 = Y(i, j, 2), y3 = Y(i, j, 3);
  const float right_c = y0 / (Y(ip1, j, 1) + y0);
  const float left_c  = y1 / (y1 + Y(im1, j, 0));
  const float up_c    = y2 / (y2 + Y(i, jp1, 3));
  const float down_c  = y3 / (Y(i, jm1, 2) + y3);

  const float* base = inp + (size_t)b * (32 * 32 * 9);
  const int g1 = 2 * i + 1, g1m = (2 * i + 31) & 31;
  const int g2 = 2 * j + 1, g2m = (2 * j + 31) & 31;
  const float* oo = base + (g1 * 32 + g2) * 9;
  const float* oi = base + (g1 * 32 + g2m) * 9;
  const float* io = base + (g1m * 32 + g2) * 9;
  const float* ii = base + (g1m * 32 + g2m) * 9;
  const float ru = -(oo[0] + oo[3] * right_c + oo[1] * up_c) / oo[4];
  const float rd = -(oi[2] + oi[5] * right_c + oi[1] * down_c) / oi[4];
  const float lu = -(io[6] + io[3] * left_c + io[7] * up_c) / io[4];
  const float ld = -(ii[8] + ii[5] * left_c + ii[7] * down_c) / ii[4];

  float* o = out + (size_t)row * 9;
  o[0] = ld;     o[1] = left_c;  o[2] = lu;
  o[3] = down_c; o[4] = 1.0f;    o[5] = up_c;
  o[6] = rd;     o[7] = right_c; o[8] = ru;
}

// ---------------------------------------------------------------------------
extern "C" void kernel_launch(void* const* d_in, const int* in_sizes, int n_in,
                              void* d_out, int out_size, void* d_ws, size_t ws_size,
                              hipStream_t stream) {
  const float* inp  = (const float*)d_in[0];
  const float* W0   = (const float*)d_in[1];
  const float* Wa   = (const float*)d_in[2];
  const float* Wb   = (const float*)d_in[3];
  const float* B1   = (const float*)d_in[4];
  const float* B2   = (const float*)d_in[5];
  const float* B3   = (const float*)d_in[6];
  const float* B4   = (const float*)d_in[7];
  const float* M    = (const float*)d_in[8];
  const float* Wout = (const float*)d_in[9];
  const float* bout = (const float*)d_in[10];
  float* out = (float*)d_out;

  float* ws       = (float*)d_ws;
  float* x0       = ws;                            // 3,276,800 f32
  _Float16* whi   = (_Float16*)(ws + 3276800);     // 100*16384 f16 (819,200 f32)
  _Float16* wlo   = (_Float16*)(ws + 3276800 + 819200);
  float* csA      = ws + 3276800 + 819200 + 819200; // 50*128 f32

  hipLaunchKernelGGL(prep_kernel, dim3(100), dim3(256), 0, stream,
                     Wa, Wb, whi, wlo, csA);
  hipLaunchKernelGGL(first_layer_kernel, dim3(ROWS / 64), dim3(256), 0, stream,
                     inp, W0, x0);
  hipLaunchKernelGGL(chain_kernel, dim3(ROWS / RPW), dim3(256), 0, stream,
                     x0, whi, wlo, csA, B1, B2, B3, B4, M);
  hipLaunchKernelGGL(out_kernel, dim3(BATCH), dim3(256), 0, stream,
                     inp, x0, Wout, bout, out);
}